// Round 1
// baseline (327.317 us; speedup 1.0000x reference)
//
#include <hip/hip_runtime.h>
#include <hip/hip_bf16.h>
#include <hip/hip_fp16.h>
#include <type_traits>

constexpr int BB = 4;
constexpr int CC = 512;
constexpr int HH = 4096;
constexpr int IC = 256;

typedef _Float16 f16x8v __attribute__((ext_vector_type(8)));
typedef __bf16   bf16x8v __attribute__((ext_vector_type(8)));
typedef float    f32x4v __attribute__((ext_vector_type(4)));

__device__ __forceinline__ void gll16(const void* g, void* l) {
  __builtin_amdgcn_global_load_lds(
      (const __attribute__((address_space(1))) unsigned int*)g,
      (__attribute__((address_space(3))) unsigned int*)l, 16, 0, 0);
}

__device__ __forceinline__ f32x4v mfma16(f16x8v a, f16x8v b, f32x4v c) {
  return __builtin_amdgcn_mfma_f32_16x16x32_f16(a, b, c, 0, 0, 0);
}
__device__ __forceinline__ f32x4v mfma16(bf16x8v a, bf16x8v b, f32x4v c) {
  return __builtin_amdgcn_mfma_f32_16x16x32_bf16(a, b, c, 0, 0, 0);
}

__device__ __forceinline__ unsigned short hbits(float f) {
  __half h = __float2half(f);
  unsigned short b; __builtin_memcpy(&b, &h, 2); return b;
}
__device__ __forceinline__ unsigned short bbits(float f) {
  __hip_bfloat16 h = __float2bfloat16(f);
  unsigned short b; __builtin_memcpy(&b, &h, 2); return b;
}

// ---------------------------------------------------------------------------
// 128x128-tile B^T GEMM: C[m,n] = sum_k A[m,k]*B[n,k].
// 256 thr = 4 waves, each a 64x64 quadrant. C/D frag: col=lane&15,
// row=quad*4+reg -> the 4 regs span CONSECUTIVE m. All outputs are stored
// as out[n][m] (n-major), so every lane writes a PACKED 4-elem chunk.
// 2-phase prefetch: double-buffered LDS, stage tile t+1 before computing
// tile t, ONE barrier per K-step (T3-minimum; hides the HBM stage latency
// that made the old stage->sync->compute->sync loop latency-bound).
// MODE 0: DUAL theta+phi. A = w_theta/w_phi [IC,C] (sel by z>>2), B = xT.
//         out [h][ic] fp16, +bias[m=ic] (float4 bias).
// MODE 1: g.  A = xT [H,C], B = w_g [IC,C]. out gB [ic][h] bf16, +bias[n=ic].
// MODE 2: scores. A = phi (m=k), B = theta (n=q). E[q][k] = bf16(exp(s));
//         Z[b,k] += row sums (16-lane butterfly + atomics).
// MODE 3: final. A = agB [H,IC], B = w_mask [C,IC]. out[c][h] fp32
//         +bias[n=c] +xres, float4 stores.
// ---------------------------------------------------------------------------
template <int MODE>
__launch_bounds__(256)
__global__ void mgemm128(const void* __restrict__ A0, const void* __restrict__ A1,
                         const void* __restrict__ B0,
                         void* __restrict__ out0, void* __restrict__ out1,
                         const float* __restrict__ bias0, const float* __restrict__ bias1,
                         const float* __restrict__ xres, float* __restrict__ Z,
                         int M, int N, int K,
                         size_t sAb, size_t sBb, size_t sOb) {
  using ET = typename std::conditional<MODE == 3, bf16x8v, f16x8v>::type;

  __shared__ __align__(16) unsigned short sA[2][128 * 32];
  __shared__ __align__(16) unsigned short sB[2][128 * 32];

  const int zz = blockIdx.z;
  int b, which;
  if constexpr (MODE == 0) { b = zz & (BB - 1); which = zz >> 2; }
  else { b = zz; which = 0; }

  const unsigned short* __restrict__ A =
      (const unsigned short*)((MODE == 0 && which) ? A1 : A0) + (size_t)b * sAb;
  const unsigned short* __restrict__ Bm =
      (const unsigned short*)B0 + (size_t)b * sBb;
  const float* __restrict__ biasSel = (MODE == 0 && which) ? bias1 : bias0;
  void* __restrict__ outSel = (MODE == 0 && which) ? out1 : out0;

  const int t = threadIdx.x;
  const int lane = t & 63;
  const int w = t >> 6;
  const int wm = (w >> 1) << 6;
  const int wn = (w & 1) << 6;
  const int mBase = blockIdx.y * 128;
  const int nBase = blockIdx.x * 128;

  const int fr = lane & 15;
  const int fo = (lane >> 4) << 3;

  f32x4v acc[4][4] = {};

  auto stage = [&](int bi, int k0) {
#pragma unroll
    for (int p = 0; p < 2; ++p) {
      const int u = t + (p << 8);
      const int r = u >> 2;
      const int cs = (u & 3) << 3;
      gll16(A + (size_t)(mBase + r) * K + (k0 + cs), sA[bi] + u * 8);
      gll16(Bm + (size_t)(nBase + r) * K + (k0 + cs), sB[bi] + u * 8);
    }
  };

  stage(0, 0);
  __syncthreads();  // compiler drains vmcnt(0) before s_barrier
  int cur = 0;
  for (int k0 = 0; k0 < K; k0 += 32) {
    if (k0 + 32 < K) stage(cur ^ 1, k0 + 32);  // prefetch next tile
    ET af[4], bfv[4];
#pragma unroll
    for (int i = 0; i < 4; ++i)
      af[i] = *(const ET*)(sA[cur] + ((wm + (i << 4) + fr) << 5) + fo);
#pragma unroll
    for (int j = 0; j < 4; ++j)
      bfv[j] = *(const ET*)(sB[cur] + ((wn + (j << 4) + fr) << 5) + fo);
#pragma unroll
    for (int i = 0; i < 4; ++i)
#pragma unroll
      for (int j = 0; j < 4; ++j)
        acc[i][j] = mfma16(af[i], bfv[j], acc[i][j]);
    __syncthreads();  // one barrier/step: drains prefetch vmcnt + syncs reads
    cur ^= 1;
  }

  const int quad = lane >> 4;
  const int col = lane & 15;

  if constexpr (MODE == 2) {
    unsigned short* __restrict__ outB = (unsigned short*)out0;  // E [q][k]
    float zp[4][4];
#pragma unroll
    for (int i = 0; i < 4; ++i)
#pragma unroll
      for (int r = 0; r < 4; ++r) zp[i][r] = 0.f;
#pragma unroll
    for (int i = 0; i < 4; ++i) {
      const int kk0 = mBase + wm + (i << 4) + (quad << 2);
#pragma unroll
      for (int j = 0; j < 4; ++j) {
        const int q = nBase + wn + (j << 4) + col;
        const float e0 = __expf(acc[i][j][0]);
        const float e1 = __expf(acc[i][j][1]);
        const float e2 = __expf(acc[i][j][2]);
        const float e3 = __expf(acc[i][j][3]);
        zp[i][0] += e0; zp[i][1] += e1; zp[i][2] += e2; zp[i][3] += e3;
        ushort4 s = {bbits(e0), bbits(e1), bbits(e2), bbits(e3)};
        *(ushort4*)(outB + (size_t)b * sOb + (size_t)q * M + kk0) = s;
      }
    }
    // Z[k] = sum over q: butterfly across the 16 cols of each quad group
#pragma unroll
    for (int i = 0; i < 4; ++i)
#pragma unroll
      for (int r = 0; r < 4; ++r) {
        float s = zp[i][r];
        s += __shfl_xor(s, 1, 64);
        s += __shfl_xor(s, 2, 64);
        s += __shfl_xor(s, 4, 64);
        s += __shfl_xor(s, 8, 64);
        zp[i][r] = s;
      }
    if (col == 0) {
#pragma unroll
      for (int i = 0; i < 4; ++i) {
        const int kk0 = mBase + wm + (i << 4) + (quad << 2);
#pragma unroll
        for (int r = 0; r < 4; ++r)
          atomicAdd(&Z[(size_t)b * M + kk0 + r], zp[i][r]);
      }
    }
  } else {
#pragma unroll
    for (int i = 0; i < 4; ++i) {
      const int m0 = mBase + wm + (i << 4) + (quad << 2);
      float4 bv;
      if constexpr (MODE == 0) bv = *(const float4*)(biasSel + m0);
#pragma unroll
      for (int j = 0; j < 4; ++j) {
        const int n = nBase + wn + (j << 4) + col;
        if constexpr (MODE == 0) {
          ushort4 s = {hbits(acc[i][j][0] + bv.x), hbits(acc[i][j][1] + bv.y),
                       hbits(acc[i][j][2] + bv.z), hbits(acc[i][j][3] + bv.w)};
          *(ushort4*)((unsigned short*)outSel + (size_t)b * sOb +
                      (size_t)n * M + m0) = s;
        } else if constexpr (MODE == 1) {
          const float bn = bias0[n];
          ushort4 s = {bbits(acc[i][j][0] + bn), bbits(acc[i][j][1] + bn),
                       bbits(acc[i][j][2] + bn), bbits(acc[i][j][3] + bn)};
          *(ushort4*)((unsigned short*)out0 + (size_t)b * sOb +
                      (size_t)n * M + m0) = s;
        } else {  // MODE 3
          const float bn = bias0[n];
          const size_t o = (size_t)b * sOb + (size_t)n * M + m0;
          const float4 xv = *(const float4*)(xres + o);
          float4 ov = {acc[i][j][0] + bn + xv.x, acc[i][j][1] + bn + xv.y,
                       acc[i][j][2] + bn + xv.z, acc[i][j][3] + bn + xv.w};
          *(float4*)((float*)out0 + o) = ov;
        }
      }
    }
  }
}

// ---------------------------------------------------------------------------
// ag GEMM, split-K=4, NO atomics, now with 2-phase prefetch (was the most
// latency-bound kernel: VALUBusy 11%, 72us vs ~20us HBM floor).
// LDS dbuf: 2*(256x32 + 64x32)*2B = 40KB -> 4 blocks/CU = whole 1024-blk grid
// resident. Partial tile -> fp16 packed ushort4 stores into P16[kc][b][q][ic].
// ---------------------------------------------------------------------------
__launch_bounds__(256)
__global__ void mgemm_ag(const __hip_bfloat16* __restrict__ Gall,
                         const __hip_bfloat16* __restrict__ Eall,
                         unsigned short* __restrict__ P16) {
  constexpr int KC = 1024;
  __shared__ __align__(16) unsigned short sA[2][256 * 32];
  __shared__ __align__(16) unsigned short sB[2][64 * 32];

  const int b = blockIdx.z;
  const int kc = blockIdx.x;
  const int qBase = blockIdx.y * 64;
  const int k0base = kc * KC;

  const unsigned short* __restrict__ G =
      (const unsigned short*)Gall + (size_t)b * IC * HH;
  const unsigned short* __restrict__ E =
      (const unsigned short*)Eall + (size_t)b * HH * HH;

  const int t = threadIdx.x;
  const int lane = t & 63;
  const int w = t >> 6;
  const int fr = lane & 15;
  const int fo = (lane >> 4) << 3;

  f32x4v acc[4][4] = {};

  auto stage = [&](int bi, int k0) {
#pragma unroll
    for (int p = 0; p < 4; ++p) {
      const int u = t + (p << 8);
      const int r = u >> 2;
      const int cs = (u & 3) << 3;
      gll16(G + (size_t)r * HH + (k0 + cs), sA[bi] + u * 8);
    }
    {
      const int r = t >> 2;
      const int cs = (t & 3) << 3;
      gll16(E + (size_t)(qBase + r) * HH + (k0 + cs), sB[bi] + t * 8);
    }
  };

  stage(0, k0base);
  __syncthreads();
  int cur = 0;
  for (int kk = 0; kk < KC; kk += 32) {
    if (kk + 32 < KC) stage(cur ^ 1, k0base + kk + 32);  // prefetch
    bf16x8v af[4], bfv[4];
#pragma unroll
    for (int i = 0; i < 4; ++i)
      af[i] = *(const bf16x8v*)(sA[cur] + (((w << 6) + (i << 4) + fr) << 5) + fo);
#pragma unroll
    for (int j = 0; j < 4; ++j)
      bfv[j] = *(const bf16x8v*)(sB[cur] + (((j << 4) + fr) << 5) + fo);
#pragma unroll
    for (int i = 0; i < 4; ++i)
#pragma unroll
      for (int j = 0; j < 4; ++j)
        acc[i][j] = mfma16(af[i], bfv[j], acc[i][j]);
    __syncthreads();
    cur ^= 1;
  }

  // D layout: col(n=q)=lane&15, row(m=ic)=quad*4+reg -> packed 8B ushort4
  unsigned short* __restrict__ P =
      P16 + ((size_t)kc * BB + b) * HH * IC;
  const int quad = lane >> 4;
  const int col = lane & 15;
#pragma unroll
  for (int i = 0; i < 4; ++i) {
    const int ic0 = (w << 6) + (i << 4) + (quad << 2);
#pragma unroll
    for (int j = 0; j < 4; ++j) {
      const int q = qBase + (j << 4) + col;
      ushort4 s = {hbits(acc[i][j][0]), hbits(acc[i][j][1]),
                   hbits(acc[i][j][2]), hbits(acc[i][j][3])};
      *(ushort4*)(P + (size_t)q * IC + ic0) = s;
    }
  }
}

// agB[b,q,ic] = bf16( sum_kc fp16 P16[kc][b][q][ic] ), 8 elems/thread
__launch_bounds__(256)
__global__ void cvt_ag(const unsigned short* __restrict__ P16,
                       __hip_bfloat16* __restrict__ agB) {
  constexpr size_t CH = (size_t)BB * HH * IC;
  const size_t tIdx = (size_t)blockIdx.x * 256 + threadIdx.x;
  const f16x8v v0 = ((const f16x8v*)(P16))[tIdx];
  const f16x8v v1 = ((const f16x8v*)(P16 + CH))[tIdx];
  const f16x8v v2 = ((const f16x8v*)(P16 + 2 * CH))[tIdx];
  const f16x8v v3 = ((const f16x8v*)(P16 + 3 * CH))[tIdx];
  unsigned short o[8];
#pragma unroll
  for (int k = 0; k < 8; ++k) {
    const float s = (float)v0[k] + (float)v1[k] + (float)v2[k] + (float)v3[k];
    o[k] = bbits(s);
  }
  uint4 pack;
  __builtin_memcpy(&pack, o, 16);
  ((uint4*)agB)[tIdx] = pack;
}

// x [B,C,H] fp32 -> xT [B,H,C] fp16
__launch_bounds__(256)
__global__ void xpose(const float* __restrict__ x, __half* __restrict__ xT) {
  __shared__ float tile[64][65];
  const int b = blockIdx.z;
  const int h0 = blockIdx.x * 64;
  const int c0 = blockIdx.y * 64;
  const int lane = threadIdx.x & 63;
  const int r0 = threadIdx.x >> 6;
  const float* xb = x + (size_t)b * CC * HH;
#pragma unroll
  for (int rr = 0; rr < 16; ++rr) {
    const int c = r0 * 16 + rr;
    tile[c][lane] = xb[(size_t)(c0 + c) * HH + h0 + lane];
  }
  __syncthreads();
  __half* ob = xT + (size_t)b * HH * CC;
#pragma unroll
  for (int rr = 0; rr < 16; ++rr) {
    const int hl = r0 * 16 + rr;
    ob[(size_t)(h0 + hl) * CC + c0 + lane] = __float2half(tile[lane][hl]);
  }
}

__global__ void convw(const float* __restrict__ s0, const float* __restrict__ s1,
                      const float* __restrict__ s2, const float* __restrict__ s3,
                      __half* __restrict__ d0, __half* __restrict__ d1,
                      __half* __restrict__ d2, __hip_bfloat16* __restrict__ d3) {
  const int which = blockIdx.y;
  const int i = (blockIdx.x * 256 + threadIdx.x) * 4;
  if (which < 3) {
    const float* s = which == 0 ? s0 : (which == 1 ? s1 : s2);
    __half* d = which == 0 ? d0 : (which == 1 ? d1 : d2);
    const float4 v = *(const float4*)(s + i);
    d[i] = __float2half(v.x); d[i + 1] = __float2half(v.y);
    d[i + 2] = __float2half(v.z); d[i + 3] = __float2half(v.w);
  } else {
    const float4 v = *(const float4*)(s3 + i);
    d3[i] = __float2bfloat16(v.x); d3[i + 1] = __float2bfloat16(v.y);
    d3[i + 2] = __float2bfloat16(v.z); d3[i + 3] = __float2bfloat16(v.w);
  }
}

// gB [B,IC,H] bf16 /= Z[b,h]
__launch_bounds__(256)
__global__ void gscale(unsigned int* __restrict__ g, const float* __restrict__ Z) {
  const size_t tid = (size_t)blockIdx.x * 256 + threadIdx.x;
  const size_t e0 = tid * 8;
  const int b = (int)(e0 >> 20);
  const int h = (int)(e0 & (HH - 1));
  const float* Zp = Z + ((size_t)b << 12) + h;
  uint4 raw = ((const uint4*)g)[tid];
  unsigned short* u = (unsigned short*)&raw;
#pragma unroll
  for (int k = 0; k < 8; ++k) {
    const float f = __uint_as_float(((unsigned)u[k]) << 16) / Zp[k];
    u[k] = bbits(f);
  }
  ((uint4*)g)[tid] = raw;
}

// ---------------------------------------------------------------------------
extern "C" void kernel_launch(void* const* d_in, const int* in_sizes, int n_in,
                              void* d_out, int out_size, void* d_ws, size_t ws_size,
                              hipStream_t stream) {
  (void)in_sizes; (void)n_in; (void)out_size; (void)ws_size;

  const float* x       = (const float*)d_in[0];
  const float* w_phi   = (const float*)d_in[1];
  const float* b_phi   = (const float*)d_in[2];
  const float* w_theta = (const float*)d_in[3];
  const float* b_theta = (const float*)d_in[4];
  const float* w_g     = (const float*)d_in[5];
  const float* b_g     = (const float*)d_in[6];
  const float* w_mask  = (const float*)d_in[7];
  const float* b_mask  = (const float*)d_in[8];
  float* out = (float*)d_out;

  char* p = (char*)d_ws;
  __hip_bfloat16* E = (__hip_bfloat16*)p;           p += (size_t)BB * HH * HH * 2;   // [q][k]
  __half* xT       = (__half*)p;                    p += (size_t)BB * HH * CC * 2;   // 16.8 MB
  __half* thetaH   = (__half*)p;                    p += (size_t)BB * HH * IC * 2;   // [h][ic]
  __half* phiH     = (__half*)p;                    p += (size_t)BB * HH * IC * 2;   // [h][ic]
  __hip_bfloat16* gB  = (__hip_bfloat16*)p;         p += (size_t)BB * IC * HH * 2;   // [ic][h]
  __hip_bfloat16* agB = (__hip_bfloat16*)p;         p += (size_t)BB * HH * IC * 2;   // [h][ic]
  __half* wthH = (__half*)p;                        p += (size_t)IC * CC * 2;
  __half* wphH = (__half*)p;                        p += (size_t)IC * CC * 2;
  __half* wgH  = (__half*)p;                        p += (size_t)IC * CC * 2;
  __hip_bfloat16* wmB = (__hip_bfloat16*)p;         p += (size_t)CC * IC * 2;
  float* Z = (float*)p;                             p += (size_t)BB * HH * 4;
  // fp16 split-K partials (4 x 8.4 MB = 33.6 MB) alias xT+theta+phi, all dead
  // by the time mgemm_ag runs.
  unsigned short* P16 = (unsigned short*)xT;

  const dim3 blk(256);

  convw<<<dim3(128, 4), blk, 0, stream>>>(w_phi, w_theta, w_g, w_mask, wphH, wthH, wgH, wmB);
  xpose<<<dim3(HH / 64, CC / 64, BB), blk, 0, stream>>>(x, xT);

  // theta/phi dual: A = w_theta/w_phi [IC,C] (m=ic), B = xT [H,C] (n=h);
  // out [h][ic] fp16, +bias[m], packed ushort4 stores.
  mgemm128<0><<<dim3(HH / 128, IC / 128, BB * 2), blk, 0, stream>>>(
      wthH, wphH, xT, thetaH, phiH, b_theta, b_phi, nullptr, nullptr,
      IC, HH, CC, 0, (size_t)HH * CC, (size_t)HH * IC);

  // g: A = xT [H,C] (m=h), B = wg [IC,C] (n=ic); out gB[ic][h] bf16, +bias[n]
  mgemm128<1><<<dim3(IC / 128, HH / 128, BB), blk, 0, stream>>>(
      xT, nullptr, wgH, gB, nullptr, b_g, nullptr, nullptr, nullptr,
      HH, IC, CC, (size_t)HH * CC, 0, (size_t)IC * HH);

  // scores: A = phi (m=k), B = theta (n=q); E[q][k] bf16 packed + Z[b,k]
  hipMemsetAsync(Z, 0, (size_t)BB * HH * sizeof(float), stream);
  mgemm128<2><<<dim3(HH / 128, HH / 128, BB), blk, 0, stream>>>(
      phiH, nullptr, thetaH, E, nullptr, nullptr, nullptr, nullptr, Z,
      HH, HH, IC, (size_t)HH * IC, (size_t)HH * IC, (size_t)HH * HH);

  gscale<<<dim3((BB * IC * HH / 8) / 256), blk, 0, stream>>>((unsigned int*)gB, Z);

  // ag: split-K=4, fp16 partials, no atomics, prefetched
  mgemm_ag<<<dim3(4, HH / 64, BB), blk, 0, stream>>>(gB, E, P16);
  cvt_ag<<<dim3((BB * HH * IC / 8) / 256), blk, 0, stream>>>(P16, agB);

  // final: A = agB [H,IC] (m=h), B = wm [C,IC] (n=c); out[c][h] fp32
  // +bias[n] +x, float4 stores.
  mgemm128<3><<<dim3(CC / 128, HH / 128, BB), blk, 0, stream>>>(
      agB, nullptr, wmB, out, nullptr, b_mask, nullptr, x, nullptr,
      HH, CC, IC, (size_t)HH * IC, 0, (size_t)CC * HH);
}

// Round 2
// 296.497 us; speedup vs baseline: 1.1039x; 1.1039x over previous
//
#include <hip/hip_runtime.h>
#include <hip/hip_bf16.h>
#include <hip/hip_fp16.h>
#include <type_traits>

constexpr int BB = 4;
constexpr int CC = 512;
constexpr int HH = 4096;
constexpr int IC = 256;

typedef _Float16 f16x8v __attribute__((ext_vector_type(8)));
typedef __bf16   bf16x8v __attribute__((ext_vector_type(8)));
typedef float    f32x4v __attribute__((ext_vector_type(4)));

__device__ __forceinline__ void gll16(const void* g, void* l) {
  __builtin_amdgcn_global_load_lds(
      (const __attribute__((address_space(1))) unsigned int*)g,
      (__attribute__((address_space(3))) unsigned int*)l, 16, 0, 0);
}

__device__ __forceinline__ f32x4v mfma16(f16x8v a, f16x8v b, f32x4v c) {
  return __builtin_amdgcn_mfma_f32_16x16x32_f16(a, b, c, 0, 0, 0);
}
__device__ __forceinline__ f32x4v mfma16(bf16x8v a, bf16x8v b, f32x4v c) {
  return __builtin_amdgcn_mfma_f32_16x16x32_bf16(a, b, c, 0, 0, 0);
}

__device__ __forceinline__ unsigned short hbits(float f) {
  __half h = __float2half(f);
  unsigned short b; __builtin_memcpy(&b, &h, 2); return b;
}
__device__ __forceinline__ unsigned short bbits(float f) {
  __hip_bfloat16 h = __float2bfloat16(f);
  unsigned short b; __builtin_memcpy(&b, &h, 2); return b;
}

// ---------------------------------------------------------------------------
// 128x128-tile B^T GEMM (round-0 PROVEN version — reverted after round-1's
// swapped-epilogue inflated WRITE_SIZE 135->200MB; stores must stay
// contiguous within 16 consecutive lanes).
// C[m,n] = sum_k A[m,k]*B[n,k]. 256 thr = 4 waves, each a 64x64 quadrant.
// C/D: col=lane&15, row=quad*4+reg.
// MODE 0: DUAL theta+phi (blockIdx.z>>2 selects B/bias/out). fp16, +bias[n].
// MODE 1: bf16, +bias[m]                       (g proj -> gB [IC,H])
// MODE 2: bf16 exp(v); Z[b,n] += column sums   (scores -> E [q,k])
// MODE 3: fp32, +bias[m] + xres                (final + residual)
// ---------------------------------------------------------------------------
template <int MODE>
__launch_bounds__(256)
__global__ void mgemm128(const void* __restrict__ Aall, const void* __restrict__ Ball,
                         const void* __restrict__ Ball2,
                         void* __restrict__ outP, void* __restrict__ out2P,
                         const float* __restrict__ bias, const float* __restrict__ bias2,
                         const float* __restrict__ xres, float* __restrict__ Z,
                         int M, int N, int K,
                         size_t sAb, size_t sBb, size_t sOb) {
  using ET = typename std::conditional<MODE == 3, bf16x8v, f16x8v>::type;

  __shared__ __align__(16) unsigned short sA[128 * 32];
  __shared__ __align__(16) unsigned short sB[128 * 32];

  const int zz = blockIdx.z;
  int b, which;
  if constexpr (MODE == 0) { b = zz & (BB - 1); which = zz >> 2; }
  else { b = zz; which = 0; }

  const unsigned short* __restrict__ A = (const unsigned short*)Aall + (size_t)b * sAb;
  const unsigned short* __restrict__ Bm =
      (const unsigned short*)((MODE == 0 && which) ? Ball2 : Ball) + (size_t)b * sBb;
  const float* __restrict__ biasSel = (MODE == 0 && which) ? bias2 : bias;
  void* __restrict__ outSel = (MODE == 0 && which) ? out2P : outP;

  const int t = threadIdx.x;
  const int lane = t & 63;
  const int w = t >> 6;
  const int wm = (w >> 1) << 6;
  const int wn = (w & 1) << 6;
  const int mBase = blockIdx.y * 128;
  const int nBase = blockIdx.x * 128;

  const int fr = lane & 15;
  const int fo = (lane >> 4) << 3;

  f32x4v acc[4][4] = {};

  for (int k0 = 0; k0 < K; k0 += 32) {
#pragma unroll
    for (int p = 0; p < 2; ++p) {
      const int u = t + (p << 8);
      const int r = u >> 2;
      const int cs = (u & 3) << 3;
      gll16(A + (size_t)(mBase + r) * K + (k0 + cs), sA + u * 8);
      gll16(Bm + (size_t)(nBase + r) * K + (k0 + cs), sB + u * 8);
    }
    __syncthreads();
    ET af[4], bf[4];
#pragma unroll
    for (int i = 0; i < 4; ++i)
      af[i] = *(const ET*)(sA + ((wm + (i << 4) + fr) << 5) + fo);
#pragma unroll
    for (int j = 0; j < 4; ++j)
      bf[j] = *(const ET*)(sB + ((wn + (j << 4) + fr) << 5) + fo);
#pragma unroll
    for (int i = 0; i < 4; ++i)
#pragma unroll
      for (int j = 0; j < 4; ++j)
        acc[i][j] = mfma16(af[i], bf[j], acc[i][j]);
    __syncthreads();
  }

  const int row0 = (lane >> 4) << 2;
  const int col = lane & 15;

  if constexpr (MODE == 2) {
    __hip_bfloat16* __restrict__ outB = (__hip_bfloat16*)outP;
    float csum[4] = {0.f, 0.f, 0.f, 0.f};
#pragma unroll
    for (int i = 0; i < 4; ++i) {
      const int m0 = mBase + wm + (i << 4) + row0;
#pragma unroll
      for (int j = 0; j < 4; ++j) {
        const int n = nBase + wn + (j << 4) + col;
        __hip_bfloat16* dst = outB + (size_t)b * sOb + (size_t)m0 * N + n;
#pragma unroll
        for (int rg = 0; rg < 4; ++rg) {
          const float e = __expf(acc[i][j][rg]);
          dst[(size_t)rg * N] = __float2bfloat16(e);
          csum[j] += e;
        }
      }
    }
#pragma unroll
    for (int j = 0; j < 4; ++j) {
      float s = csum[j];
      s += __shfl_xor(s, 16, 64);
      s += __shfl_xor(s, 32, 64);
      if (lane < 16) {
        const int n = nBase + wn + (j << 4) + col;
        atomicAdd(&Z[(size_t)b * N + n], s);
      }
    }
  } else {
#pragma unroll
    for (int i = 0; i < 4; ++i) {
      const int m0 = mBase + wm + (i << 4) + row0;
#pragma unroll
      for (int j = 0; j < 4; ++j) {
        const int n = nBase + wn + (j << 4) + col;
#pragma unroll
        for (int rg = 0; rg < 4; ++rg) {
          const int m = m0 + rg;
          const float v = acc[i][j][rg];
          if constexpr (MODE == 0) {
            ((__half*)outSel)[(size_t)b * sOb + (size_t)m * N + n] =
                __float2half(v + biasSel[n]);
          } else if constexpr (MODE == 1) {
            ((__hip_bfloat16*)outP)[(size_t)b * sOb + (size_t)m * N + n] =
                __float2bfloat16(v + bias[m]);
          } else {
            const size_t o = (size_t)b * sOb + (size_t)m * N + n;
            ((float*)outP)[o] = v + bias[m] + xres[o];
          }
        }
      }
    }
  }
}

// ---------------------------------------------------------------------------
// ag GEMM, split-K=4, NO atomics. Double-buffered with STATIC buffer indices
// (2 K-steps unrolled per iteration) so the compiler can disambiguate the
// prefetch gll16 writes (sA[1]) from the current ds_reads (sA[0]) and keep
// the prefetch in flight across the compute phase. Round-0 (no prefetch)
// was latency-bound: VALUBusy 11%, 72us vs ~25us floor.
// LDS: 2*(256x32 + 64x32)*2B = 40KB -> 4 blocks/CU = whole 1024-blk grid
// resident. Partial tile -> fp16 packed ushort4 stores into P16[kc][b][q][ic]
// (4 stride-16 lanes form contiguous 32B — no write inflation, verified r1).
// ---------------------------------------------------------------------------
__launch_bounds__(256)
__global__ void mgemm_ag(const __hip_bfloat16* __restrict__ Gall,
                         const __hip_bfloat16* __restrict__ Eall,
                         unsigned short* __restrict__ P16) {
  constexpr int KC = 1024;
  __shared__ __align__(16) unsigned short sA[2][256 * 32];
  __shared__ __align__(16) unsigned short sB[2][64 * 32];

  const int b = blockIdx.z;
  const int kc = blockIdx.x;
  const int qBase = blockIdx.y * 64;
  const int k0base = kc * KC;

  const unsigned short* __restrict__ G =
      (const unsigned short*)Gall + (size_t)b * IC * HH;
  const unsigned short* __restrict__ E =
      (const unsigned short*)Eall + (size_t)b * HH * HH;

  const int t = threadIdx.x;
  const int lane = t & 63;
  const int w = t >> 6;
  const int fr = lane & 15;
  const int fo = (lane >> 4) << 3;

  f32x4v acc[4][4] = {};

  auto stage = [&](unsigned short* dA, unsigned short* dB, int k0) {
#pragma unroll
    for (int p = 0; p < 4; ++p) {
      const int u = t + (p << 8);
      const int r = u >> 2;
      const int cs = (u & 3) << 3;
      gll16(G + (size_t)r * HH + (k0 + cs), dA + u * 8);
    }
    {
      const int r = t >> 2;
      const int cs = (t & 3) << 3;
      gll16(E + (size_t)(qBase + r) * HH + (k0 + cs), dB + t * 8);
    }
  };

  auto compute = [&](const unsigned short* pA, const unsigned short* pB) {
    bf16x8v af[4], bfv[4];
#pragma unroll
    for (int i = 0; i < 4; ++i)
      af[i] = *(const bf16x8v*)(pA + (((w << 6) + (i << 4) + fr) << 5) + fo);
#pragma unroll
    for (int j = 0; j < 4; ++j)
      bfv[j] = *(const bf16x8v*)(pB + (((j << 4) + fr) << 5) + fo);
#pragma unroll
    for (int i = 0; i < 4; ++i)
#pragma unroll
      for (int j = 0; j < 4; ++j)
        acc[i][j] = mfma16(af[i], bfv[j], acc[i][j]);
  };

  stage(sA[0], sB[0], k0base);
  __syncthreads();
  for (int kk = 0; kk < KC; kk += 64) {
    // prefetch step kk+32 into buffer 1 while computing buffer 0
    stage(sA[1], sB[1], k0base + kk + 32);
    compute(sA[0], sB[0]);
    __syncthreads();
    // prefetch step kk+64 into buffer 0 while computing buffer 1
    if (kk + 64 < KC) stage(sA[0], sB[0], k0base + kk + 64);
    compute(sA[1], sB[1]);
    __syncthreads();
  }

  // D layout: col(n=q)=lane&15, row(m=ic)=quad*4+reg -> packed 8B ushort4
  unsigned short* __restrict__ P =
      P16 + ((size_t)kc * BB + b) * HH * IC;
  const int quad = lane >> 4;
  const int col = lane & 15;
#pragma unroll
  for (int i = 0; i < 4; ++i) {
    const int ic0 = (w << 6) + (i << 4) + (quad << 2);
#pragma unroll
    for (int j = 0; j < 4; ++j) {
      const int q = qBase + (j << 4) + col;
      ushort4 s = {hbits(acc[i][j][0]), hbits(acc[i][j][1]),
                   hbits(acc[i][j][2]), hbits(acc[i][j][3])};
      *(ushort4*)(P + (size_t)q * IC + ic0) = s;
    }
  }
}

// agB[b,q,ic] = bf16( sum_kc fp16 P16[kc][b][q][ic] ), 8 elems/thread
__launch_bounds__(256)
__global__ void cvt_ag(const unsigned short* __restrict__ P16,
                       __hip_bfloat16* __restrict__ agB) {
  constexpr size_t CH = (size_t)BB * HH * IC;
  const size_t tIdx = (size_t)blockIdx.x * 256 + threadIdx.x;
  const f16x8v v0 = ((const f16x8v*)(P16))[tIdx];
  const f16x8v v1 = ((const f16x8v*)(P16 + CH))[tIdx];
  const f16x8v v2 = ((const f16x8v*)(P16 + 2 * CH))[tIdx];
  const f16x8v v3 = ((const f16x8v*)(P16 + 3 * CH))[tIdx];
  unsigned short o[8];
#pragma unroll
  for (int k = 0; k < 8; ++k) {
    const float s = (float)v0[k] + (float)v1[k] + (float)v2[k] + (float)v3[k];
    o[k] = bbits(s);
  }
  uint4 pack;
  __builtin_memcpy(&pack, o, 16);
  ((uint4*)agB)[tIdx] = pack;
}

// x [B,C,H] fp32 -> xT [B,H,C] fp16
__launch_bounds__(256)
__global__ void xpose(const float* __restrict__ x, __half* __restrict__ xT) {
  __shared__ float tile[64][65];
  const int b = blockIdx.z;
  const int h0 = blockIdx.x * 64;
  const int c0 = blockIdx.y * 64;
  const int lane = threadIdx.x & 63;
  const int r0 = threadIdx.x >> 6;
  const float* xb = x + (size_t)b * CC * HH;
#pragma unroll
  for (int rr = 0; rr < 16; ++rr) {
    const int c = r0 * 16 + rr;
    tile[c][lane] = xb[(size_t)(c0 + c) * HH + h0 + lane];
  }
  __syncthreads();
  __half* ob = xT + (size_t)b * HH * CC;
#pragma unroll
  for (int rr = 0; rr < 16; ++rr) {
    const int hl = r0 * 16 + rr;
    ob[(size_t)(h0 + hl) * CC + c0 + lane] = __float2half(tile[lane][hl]);
  }
}

__global__ void convw(const float* __restrict__ s0, const float* __restrict__ s1,
                      const float* __restrict__ s2, const float* __restrict__ s3,
                      __half* __restrict__ d0, __half* __restrict__ d1,
                      __half* __restrict__ d2, __hip_bfloat16* __restrict__ d3) {
  const int which = blockIdx.y;
  const int i = (blockIdx.x * 256 + threadIdx.x) * 4;
  if (which < 3) {
    const float* s = which == 0 ? s0 : (which == 1 ? s1 : s2);
    __half* d = which == 0 ? d0 : (which == 1 ? d1 : d2);
    const float4 v = *(const float4*)(s + i);
    d[i] = __float2half(v.x); d[i + 1] = __float2half(v.y);
    d[i + 2] = __float2half(v.z); d[i + 3] = __float2half(v.w);
  } else {
    const float4 v = *(const float4*)(s3 + i);
    d3[i] = __float2bfloat16(v.x); d3[i + 1] = __float2bfloat16(v.y);
    d3[i + 2] = __float2bfloat16(v.z); d3[i + 3] = __float2bfloat16(v.w);
  }
}

// gB [B,IC,H] bf16 /= Z[b,h]
__launch_bounds__(256)
__global__ void gscale(unsigned int* __restrict__ g, const float* __restrict__ Z) {
  const size_t tid = (size_t)blockIdx.x * 256 + threadIdx.x;
  const size_t e0 = tid * 8;
  const int b = (int)(e0 >> 20);
  const int h = (int)(e0 & (HH - 1));
  const float* Zp = Z + ((size_t)b << 12) + h;
  uint4 raw = ((const uint4*)g)[tid];
  unsigned short* u = (unsigned short*)&raw;
#pragma unroll
  for (int k = 0; k < 8; ++k) {
    const float f = __uint_as_float(((unsigned)u[k]) << 16) / Zp[k];
    u[k] = bbits(f);
  }
  ((uint4*)g)[tid] = raw;
}

// ---------------------------------------------------------------------------
extern "C" void kernel_launch(void* const* d_in, const int* in_sizes, int n_in,
                              void* d_out, int out_size, void* d_ws, size_t ws_size,
                              hipStream_t stream) {
  (void)in_sizes; (void)n_in; (void)out_size; (void)ws_size;

  const float* x       = (const float*)d_in[0];
  const float* w_phi   = (const float*)d_in[1];
  const float* b_phi   = (const float*)d_in[2];
  const float* w_theta = (const float*)d_in[3];
  const float* b_theta = (const float*)d_in[4];
  const float* w_g     = (const float*)d_in[5];
  const float* b_g     = (const float*)d_in[6];
  const float* w_mask  = (const float*)d_in[7];
  const float* b_mask  = (const float*)d_in[8];
  float* out = (float*)d_out;

  char* p = (char*)d_ws;
  __hip_bfloat16* E = (__hip_bfloat16*)p;           p += (size_t)BB * HH * HH * 2;   // [q][k]
  __half* xT       = (__half*)p;                    p += (size_t)BB * HH * CC * 2;   // 16.8 MB
  __half* thetaH   = (__half*)p;                    p += (size_t)BB * HH * IC * 2;   // [h][ic]
  __half* phiH     = (__half*)p;                    p += (size_t)BB * HH * IC * 2;   // [h][ic]
  __hip_bfloat16* gB  = (__hip_bfloat16*)p;         p += (size_t)BB * IC * HH * 2;   // [ic][h]
  __hip_bfloat16* agB = (__hip_bfloat16*)p;         p += (size_t)BB * HH * IC * 2;   // [h][ic]
  __half* wthH = (__half*)p;                        p += (size_t)IC * CC * 2;
  __half* wphH = (__half*)p;                        p += (size_t)IC * CC * 2;
  __half* wgH  = (__half*)p;                        p += (size_t)IC * CC * 2;
  __hip_bfloat16* wmB = (__hip_bfloat16*)p;         p += (size_t)CC * IC * 2;
  float* Z = (float*)p;                             p += (size_t)BB * HH * 4;
  // fp16 split-K partials (4 x 8.4 MB = 33.6 MB) alias xT+theta+phi, all dead
  // by the time mgemm_ag runs.
  unsigned short* P16 = (unsigned short*)xT;

  const dim3 blk(256);

  convw<<<dim3(128, 4), blk, 0, stream>>>(w_phi, w_theta, w_g, w_mask, wphH, wthH, wgH, wmB);
  xpose<<<dim3(HH / 64, CC / 64, BB), blk, 0, stream>>>(x, xT);

  // theta/phi dual: A=xT [H,C], B=w_theta/w_phi [IC,C]; out [h][ic] fp16, +bias[ic]
  mgemm128<0><<<dim3(IC / 128, HH / 128, BB * 2), blk, 0, stream>>>(
      xT, wthH, wphH, thetaH, phiH, b_theta, b_phi, nullptr, nullptr,
      HH, IC, CC, (size_t)HH * CC, 0, (size_t)HH * IC);

  // g: A=wg [IC,C], B=xT [H,C]; out gB[ic][h] bf16, +bias[ic=m]
  mgemm128<1><<<dim3(HH / 128, IC / 128, BB), blk, 0, stream>>>(
      wgH, xT, nullptr, gB, nullptr, b_g, nullptr, nullptr, nullptr,
      IC, HH, CC, 0, (size_t)HH * CC, (size_t)IC * HH);

  // scores: A=theta (m=q), B=phi (n=k); E[q][k] bf16 + Z[b,k]
  hipMemsetAsync(Z, 0, (size_t)BB * HH * sizeof(float), stream);
  mgemm128<2><<<dim3(HH / 128, HH / 128, BB), blk, 0, stream>>>(
      thetaH, phiH, nullptr, E, nullptr, nullptr, nullptr, nullptr, Z,
      HH, HH, IC, (size_t)HH * IC, (size_t)HH * IC, (size_t)HH * HH);

  gscale<<<dim3((BB * IC * HH / 8) / 256), blk, 0, stream>>>((unsigned int*)gB, Z);

  // ag: split-K=4, fp16 partials, no atomics, static-dbuf prefetch
  mgemm_ag<<<dim3(4, HH / 64, BB), blk, 0, stream>>>(gB, E, P16);
  cvt_ag<<<dim3((BB * HH * IC / 8) / 256), blk, 0, stream>>>(P16, agB);

  // final: A=wm [C,IC], B=agB [H,IC]; out[c][h] fp32 + bias[c] + x
  mgemm128<3><<<dim3(HH / 128, CC / 128, BB), blk, 0, stream>>>(
      wmB, agB, nullptr, out, nullptr, b_mask, nullptr, x, nullptr,
      CC, HH, IC, 0, (size_t)HH * IC, (size_t)CC * HH);
}

// Round 3
// 266.928 us; speedup vs baseline: 1.2262x; 1.1108x over previous
//
#include <hip/hip_runtime.h>
#include <hip/hip_bf16.h>
#include <hip/hip_fp16.h>
#include <type_traits>

constexpr int BB = 4;
constexpr int CC = 512;
constexpr int HH = 4096;
constexpr int IC = 256;

typedef _Float16 f16x8v __attribute__((ext_vector_type(8)));
typedef __bf16   bf16x8v __attribute__((ext_vector_type(8)));
typedef float    f32x4v __attribute__((ext_vector_type(4)));

__device__ __forceinline__ void gll16(const void* g, void* l) {
  __builtin_amdgcn_global_load_lds(
      (const __attribute__((address_space(1))) unsigned int*)g,
      (__attribute__((address_space(3))) unsigned int*)l, 16, 0, 0);
}

__device__ __forceinline__ f32x4v mfma16(f16x8v a, f16x8v b, f32x4v c) {
  return __builtin_amdgcn_mfma_f32_16x16x32_f16(a, b, c, 0, 0, 0);
}
__device__ __forceinline__ f32x4v mfma16(bf16x8v a, bf16x8v b, f32x4v c) {
  return __builtin_amdgcn_mfma_f32_16x16x32_bf16(a, b, c, 0, 0, 0);
}

__device__ __forceinline__ unsigned short hbits(float f) {
  __half h = __float2half(f);
  unsigned short b; __builtin_memcpy(&b, &h, 2); return b;
}
__device__ __forceinline__ unsigned short bbits(float f) {
  __hip_bfloat16 h = __float2bfloat16(f);
  unsigned short b; __builtin_memcpy(&b, &h, 2); return b;
}

// ---------------------------------------------------------------------------
// 128x128-tile B^T GEMM (round-0 PROVEN version; round-1's swapped epilogue
// inflated WRITE_SIZE 135->200MB — stores must stay contiguous within 16
// consecutive lanes).
// C[m,n] = sum_k A[m,k]*B[n,k]. 256 thr = 4 waves, each a 64x64 quadrant.
// C/D: col=lane&15, row=quad*4+reg.
// MODE 0: DUAL theta+phi (blockIdx.z>>2 selects B/bias/out). fp16, +bias[n].
// MODE 1: bf16, +bias[m]                       (g proj -> gB [IC,H])
// MODE 2: bf16 exp(v); Z[b,n] += column sums   (scores -> E [q,k])
// MODE 3: fp32, +bias[m] + xres                (final + residual)
// ---------------------------------------------------------------------------
template <int MODE>
__launch_bounds__(256)
__global__ void mgemm128(const void* __restrict__ Aall, const void* __restrict__ Ball,
                         const void* __restrict__ Ball2,
                         void* __restrict__ outP, void* __restrict__ out2P,
                         const float* __restrict__ bias, const float* __restrict__ bias2,
                         const float* __restrict__ xres, float* __restrict__ Z,
                         int M, int N, int K,
                         size_t sAb, size_t sBb, size_t sOb) {
  using ET = typename std::conditional<MODE == 3, bf16x8v, f16x8v>::type;

  __shared__ __align__(16) unsigned short sA[128 * 32];
  __shared__ __align__(16) unsigned short sB[128 * 32];

  const int zz = blockIdx.z;
  int b, which;
  if constexpr (MODE == 0) { b = zz & (BB - 1); which = zz >> 2; }
  else { b = zz; which = 0; }

  const unsigned short* __restrict__ A = (const unsigned short*)Aall + (size_t)b * sAb;
  const unsigned short* __restrict__ Bm =
      (const unsigned short*)((MODE == 0 && which) ? Ball2 : Ball) + (size_t)b * sBb;
  const float* __restrict__ biasSel = (MODE == 0 && which) ? bias2 : bias;
  void* __restrict__ outSel = (MODE == 0 && which) ? out2P : outP;

  const int t = threadIdx.x;
  const int lane = t & 63;
  const int w = t >> 6;
  const int wm = (w >> 1) << 6;
  const int wn = (w & 1) << 6;
  const int mBase = blockIdx.y * 128;
  const int nBase = blockIdx.x * 128;

  const int fr = lane & 15;
  const int fo = (lane >> 4) << 3;

  f32x4v acc[4][4] = {};

  for (int k0 = 0; k0 < K; k0 += 32) {
#pragma unroll
    for (int p = 0; p < 2; ++p) {
      const int u = t + (p << 8);
      const int r = u >> 2;
      const int cs = (u & 3) << 3;
      gll16(A + (size_t)(mBase + r) * K + (k0 + cs), sA + u * 8);
      gll16(Bm + (size_t)(nBase + r) * K + (k0 + cs), sB + u * 8);
    }
    __syncthreads();
    ET af[4], bf[4];
#pragma unroll
    for (int i = 0; i < 4; ++i)
      af[i] = *(const ET*)(sA + ((wm + (i << 4) + fr) << 5) + fo);
#pragma unroll
    for (int j = 0; j < 4; ++j)
      bf[j] = *(const ET*)(sB + ((wn + (j << 4) + fr) << 5) + fo);
#pragma unroll
    for (int i = 0; i < 4; ++i)
#pragma unroll
      for (int j = 0; j < 4; ++j)
        acc[i][j] = mfma16(af[i], bf[j], acc[i][j]);
    __syncthreads();
  }

  const int row0 = (lane >> 4) << 2;
  const int col = lane & 15;

  if constexpr (MODE == 2) {
    __hip_bfloat16* __restrict__ outB = (__hip_bfloat16*)outP;
    float csum[4] = {0.f, 0.f, 0.f, 0.f};
#pragma unroll
    for (int i = 0; i < 4; ++i) {
      const int m0 = mBase + wm + (i << 4) + row0;
#pragma unroll
      for (int j = 0; j < 4; ++j) {
        const int n = nBase + wn + (j << 4) + col;
        __hip_bfloat16* dst = outB + (size_t)b * sOb + (size_t)m0 * N + n;
#pragma unroll
        for (int rg = 0; rg < 4; ++rg) {
          const float e = __expf(acc[i][j][rg]);
          dst[(size_t)rg * N] = __float2bfloat16(e);
          csum[j] += e;
        }
      }
    }
#pragma unroll
    for (int j = 0; j < 4; ++j) {
      float s = csum[j];
      s += __shfl_xor(s, 16, 64);
      s += __shfl_xor(s, 32, 64);
      if (lane < 16) {
        const int n = nBase + wn + (j << 4) + col;
        atomicAdd(&Z[(size_t)b * N + n], s);
      }
    }
  } else {
#pragma unroll
    for (int i = 0; i < 4; ++i) {
      const int m0 = mBase + wm + (i << 4) + row0;
#pragma unroll
      for (int j = 0; j < 4; ++j) {
        const int n = nBase + wn + (j << 4) + col;
#pragma unroll
        for (int rg = 0; rg < 4; ++rg) {
          const int m = m0 + rg;
          const float v = acc[i][j][rg];
          if constexpr (MODE == 0) {
            ((__half*)outSel)[(size_t)b * sOb + (size_t)m * N + n] =
                __float2half(v + biasSel[n]);
          } else if constexpr (MODE == 1) {
            ((__hip_bfloat16*)outP)[(size_t)b * sOb + (size_t)m * N + n] =
                __float2bfloat16(v + bias[m]);
          } else {
            const size_t o = (size_t)b * sOb + (size_t)m * N + n;
            ((float*)outP)[o] = v + bias[m] + xres[o];
          }
        }
      }
    }
  }
}

// ---------------------------------------------------------------------------
// ag GEMM v3. ROUND-2 POST-MORTEM: no-prefetch / dbuf / static-dbuf all land
// at 72-75us pinned to ~2.0 TB/s -> NOT latency-bound; DRAM-locality-bound:
// BK=32 read E rows in 64B slivers at 8KB stride. Fix: BK=128 (256B
// contiguous per row visit) + 64 MFMA per barrier-pair.
// Split-K=2 (KC=2048): grid (2,64,4)=512 blocks, LDS 80KB -> 2 blocks/CU,
// all resident. Single-buffered (dbuf proven useless here).
// LDS rows are 256B => worst-case bank pattern, so T2 XOR-swizzle applied
// via PRE-SWIZZLED GLOBAL SOURCE (gll16 dest stays linear; 16B chunk c' at
// row r holds logical chunk c'^(r&7); reads apply same XOR). Fragments are
// exactly 16B chunks -> swizzle is chunk-granular; quarter-wave spreads 16
// rows over all 32 banks at 2-way (free).
// Partial tiles -> fp16 packed ushort4 stores into P16[kc][b][q][ic].
// ---------------------------------------------------------------------------
__launch_bounds__(256)
__global__ void mgemm_ag(const __hip_bfloat16* __restrict__ Gall,
                         const __hip_bfloat16* __restrict__ Eall,
                         unsigned short* __restrict__ P16) {
  constexpr int KC = 2048;
  constexpr int BK = 128;
  __shared__ __align__(16) unsigned short sG[256 * BK];  // 64 KB
  __shared__ __align__(16) unsigned short sE[64 * BK];   // 16 KB

  const int b = blockIdx.z;
  const int kc = blockIdx.x;            // 0..1
  const int qBase = blockIdx.y * 64;
  const int k0base = kc * KC;

  const unsigned short* __restrict__ G =
      (const unsigned short*)Gall + (size_t)b * IC * HH;
  const unsigned short* __restrict__ E =
      (const unsigned short*)Eall + (size_t)b * HH * HH;

  const int t = threadIdx.x;
  const int lane = t & 63;
  const int w = t >> 6;
  const int fr = lane & 15;
  const int fo = (lane >> 4) << 3;      // 0,8,16,24 shorts
  const int fc = fo >> 3;               // chunk sub-index 0..3

  f32x4v acc[4][4] = {};

  for (int kk = 0; kk < KC; kk += BK) {
    const int k0 = k0base + kk;
    // stage E first (HBM, long latency): 64 rows x 128k = 1024 chunks
#pragma unroll
    for (int p = 0; p < 4; ++p) {
      const int u = t + (p << 8);
      const int row = u >> 4;
      const int csrc = (u & 15) ^ (row & 7);
      gll16(E + (size_t)(qBase + row) * HH + k0 + (csrc << 3), sE + u * 8);
    }
    // stage G (mostly L2): 256 rows x 128k = 4096 chunks
#pragma unroll
    for (int p = 0; p < 16; ++p) {
      const int u = t + (p << 8);
      const int row = u >> 4;
      const int csrc = (u & 15) ^ (row & 7);
      gll16(G + (size_t)row * HH + k0 + (csrc << 3), sG + u * 8);
    }
    __syncthreads();
#pragma unroll
    for (int ks = 0; ks < 4; ++ks) {
      bf16x8v af[4], bfv[4];
      const int c16 = (ks << 2) + fc;
#pragma unroll
      for (int i = 0; i < 4; ++i) {
        const int row = (w << 6) + (i << 4) + fr;
        af[i] = *(const bf16x8v*)(sG + row * BK + ((c16 ^ (row & 7)) << 3));
      }
#pragma unroll
      for (int j = 0; j < 4; ++j) {
        const int row = (j << 4) + fr;
        bfv[j] = *(const bf16x8v*)(sE + row * BK + ((c16 ^ (row & 7)) << 3));
      }
#pragma unroll
      for (int i = 0; i < 4; ++i)
#pragma unroll
        for (int j = 0; j < 4; ++j)
          acc[i][j] = mfma16(af[i], bfv[j], acc[i][j]);
    }
    __syncthreads();
  }

  // D layout: col(n=q)=lane&15, row(m=ic)=quad*4+reg -> packed 8B ushort4
  unsigned short* __restrict__ P =
      P16 + ((size_t)kc * BB + b) * HH * IC;
  const int quad = lane >> 4;
  const int col = lane & 15;
#pragma unroll
  for (int i = 0; i < 4; ++i) {
    const int ic0 = (w << 6) + (i << 4) + (quad << 2);
#pragma unroll
    for (int j = 0; j < 4; ++j) {
      const int q = qBase + (j << 4) + col;
      ushort4 s = {hbits(acc[i][j][0]), hbits(acc[i][j][1]),
                   hbits(acc[i][j][2]), hbits(acc[i][j][3])};
      *(ushort4*)(P + (size_t)q * IC + ic0) = s;
    }
  }
}

// agB[b,q,ic] = bf16( sum over 2 split-K chunks of fp16 P16 ), 8 elems/thread
__launch_bounds__(256)
__global__ void cvt_ag(const unsigned short* __restrict__ P16,
                       __hip_bfloat16* __restrict__ agB) {
  constexpr size_t CH = (size_t)BB * HH * IC;
  const size_t tIdx = (size_t)blockIdx.x * 256 + threadIdx.x;
  const f16x8v v0 = ((const f16x8v*)(P16))[tIdx];
  const f16x8v v1 = ((const f16x8v*)(P16 + CH))[tIdx];
  unsigned short o[8];
#pragma unroll
  for (int k = 0; k < 8; ++k) {
    const float s = (float)v0[k] + (float)v1[k];
    o[k] = bbits(s);
  }
  uint4 pack;
  __builtin_memcpy(&pack, o, 16);
  ((uint4*)agB)[tIdx] = pack;
}

// x [B,C,H] fp32 -> xT [B,H,C] fp16
__launch_bounds__(256)
__global__ void xpose(const float* __restrict__ x, __half* __restrict__ xT) {
  __shared__ float tile[64][65];
  const int b = blockIdx.z;
  const int h0 = blockIdx.x * 64;
  const int c0 = blockIdx.y * 64;
  const int lane = threadIdx.x & 63;
  const int r0 = threadIdx.x >> 6;
  const float* xb = x + (size_t)b * CC * HH;
#pragma unroll
  for (int rr = 0; rr < 16; ++rr) {
    const int c = r0 * 16 + rr;
    tile[c][lane] = xb[(size_t)(c0 + c) * HH + h0 + lane];
  }
  __syncthreads();
  __half* ob = xT + (size_t)b * HH * CC;
#pragma unroll
  for (int rr = 0; rr < 16; ++rr) {
    const int hl = r0 * 16 + rr;
    ob[(size_t)(h0 + hl) * CC + c0 + lane] = __float2half(tile[lane][hl]);
  }
}

__global__ void convw(const float* __restrict__ s0, const float* __restrict__ s1,
                      const float* __restrict__ s2, const float* __restrict__ s3,
                      __half* __restrict__ d0, __half* __restrict__ d1,
                      __half* __restrict__ d2, __hip_bfloat16* __restrict__ d3) {
  const int which = blockIdx.y;
  const int i = (blockIdx.x * 256 + threadIdx.x) * 4;
  if (which < 3) {
    const float* s = which == 0 ? s0 : (which == 1 ? s1 : s2);
    __half* d = which == 0 ? d0 : (which == 1 ? d1 : d2);
    const float4 v = *(const float4*)(s + i);
    d[i] = __float2half(v.x); d[i + 1] = __float2half(v.y);
    d[i + 2] = __float2half(v.z); d[i + 3] = __float2half(v.w);
  } else {
    const float4 v = *(const float4*)(s3 + i);
    d3[i] = __float2bfloat16(v.x); d3[i + 1] = __float2bfloat16(v.y);
    d3[i + 2] = __float2bfloat16(v.z); d3[i + 3] = __float2bfloat16(v.w);
  }
}

// gB [B,IC,H] bf16 /= Z[b,h]
__launch_bounds__(256)
__global__ void gscale(unsigned int* __restrict__ g, const float* __restrict__ Z) {
  const size_t tid = (size_t)blockIdx.x * 256 + threadIdx.x;
  const size_t e0 = tid * 8;
  const int b = (int)(e0 >> 20);
  const int h = (int)(e0 & (HH - 1));
  const float* Zp = Z + ((size_t)b << 12) + h;
  uint4 raw = ((const uint4*)g)[tid];
  unsigned short* u = (unsigned short*)&raw;
#pragma unroll
  for (int k = 0; k < 8; ++k) {
    const float f = __uint_as_float(((unsigned)u[k]) << 16) / Zp[k];
    u[k] = bbits(f);
  }
  ((uint4*)g)[tid] = raw;
}

// ---------------------------------------------------------------------------
extern "C" void kernel_launch(void* const* d_in, const int* in_sizes, int n_in,
                              void* d_out, int out_size, void* d_ws, size_t ws_size,
                              hipStream_t stream) {
  (void)in_sizes; (void)n_in; (void)out_size; (void)ws_size;

  const float* x       = (const float*)d_in[0];
  const float* w_phi   = (const float*)d_in[1];
  const float* b_phi   = (const float*)d_in[2];
  const float* w_theta = (const float*)d_in[3];
  const float* b_theta = (const float*)d_in[4];
  const float* w_g     = (const float*)d_in[5];
  const float* b_g     = (const float*)d_in[6];
  const float* w_mask  = (const float*)d_in[7];
  const float* b_mask  = (const float*)d_in[8];
  float* out = (float*)d_out;

  char* p = (char*)d_ws;
  __hip_bfloat16* E = (__hip_bfloat16*)p;           p += (size_t)BB * HH * HH * 2;   // [q][k]
  __half* xT       = (__half*)p;                    p += (size_t)BB * HH * CC * 2;   // 16.8 MB
  __half* thetaH   = (__half*)p;                    p += (size_t)BB * HH * IC * 2;   // [h][ic]
  __half* phiH     = (__half*)p;                    p += (size_t)BB * HH * IC * 2;   // [h][ic]
  __hip_bfloat16* gB  = (__hip_bfloat16*)p;         p += (size_t)BB * IC * HH * 2;   // [ic][h]
  __hip_bfloat16* agB = (__hip_bfloat16*)p;         p += (size_t)BB * HH * IC * 2;   // [h][ic]
  __half* wthH = (__half*)p;                        p += (size_t)IC * CC * 2;
  __half* wphH = (__half*)p;                        p += (size_t)IC * CC * 2;
  __half* wgH  = (__half*)p;                        p += (size_t)IC * CC * 2;
  __hip_bfloat16* wmB = (__hip_bfloat16*)p;         p += (size_t)CC * IC * 2;
  float* Z = (float*)p;                             p += (size_t)BB * HH * 4;
  // fp16 split-K=2 partials (2 x 8.4 MB = 16.8 MB) alias xT exactly; xT is
  // dead by the time mgemm_ag runs.
  unsigned short* P16 = (unsigned short*)xT;

  const dim3 blk(256);

  convw<<<dim3(128, 4), blk, 0, stream>>>(w_phi, w_theta, w_g, w_mask, wphH, wthH, wgH, wmB);
  xpose<<<dim3(HH / 64, CC / 64, BB), blk, 0, stream>>>(x, xT);

  // theta/phi dual: A=xT [H,C], B=w_theta/w_phi [IC,C]; out [h][ic] fp16, +bias[ic]
  mgemm128<0><<<dim3(IC / 128, HH / 128, BB * 2), blk, 0, stream>>>(
      xT, wthH, wphH, thetaH, phiH, b_theta, b_phi, nullptr, nullptr,
      HH, IC, CC, (size_t)HH * CC, 0, (size_t)HH * IC);

  // g: A=wg [IC,C], B=xT [H,C]; out gB[ic][h] bf16, +bias[ic=m]
  mgemm128<1><<<dim3(HH / 128, IC / 128, BB), blk, 0, stream>>>(
      wgH, xT, nullptr, gB, nullptr, b_g, nullptr, nullptr, nullptr,
      IC, HH, CC, 0, (size_t)HH * CC, (size_t)IC * HH);

  // scores: A=theta (m=q), B=phi (n=k); E[q][k] bf16 + Z[b,k]
  hipMemsetAsync(Z, 0, (size_t)BB * HH * sizeof(float), stream);
  mgemm128<2><<<dim3(HH / 128, HH / 128, BB), blk, 0, stream>>>(
      thetaH, phiH, nullptr, E, nullptr, nullptr, nullptr, nullptr, Z,
      HH, HH, IC, (size_t)HH * IC, (size_t)HH * IC, (size_t)HH * HH);

  gscale<<<dim3((BB * IC * HH / 8) / 256), blk, 0, stream>>>((unsigned int*)gB, Z);

  // ag: BK=128 (256B-contiguous E reads), split-K=2, XOR-swizzled LDS
  mgemm_ag<<<dim3(2, HH / 64, BB), blk, 0, stream>>>(gB, E, P16);
  cvt_ag<<<dim3((BB * HH * IC / 8) / 256), blk, 0, stream>>>(P16, agB);

  // final: A=wm [C,IC], B=agB [H,IC]; out[c][h] fp32 + bias[c] + x
  mgemm128<3><<<dim3(HH / 128, CC / 128, BB), blk, 0, stream>>>(
      wmB, agB, nullptr, out, nullptr, b_mask, nullptr, x, nullptr,
      CC, HH, IC, 0, (size_t)HH * IC, (size_t)CC * HH);
}

// Round 4
// 262.021 us; speedup vs baseline: 1.2492x; 1.0187x over previous
//
#include <hip/hip_runtime.h>
#include <hip/hip_bf16.h>
#include <hip/hip_fp16.h>
#include <type_traits>

constexpr int BB = 4;
constexpr int CC = 512;
constexpr int HH = 4096;
constexpr int IC = 256;

typedef _Float16 f16x8v __attribute__((ext_vector_type(8)));
typedef __bf16   bf16x8v __attribute__((ext_vector_type(8)));
typedef float    f32x4v __attribute__((ext_vector_type(4)));

__device__ __forceinline__ void gll16(const void* g, void* l) {
  __builtin_amdgcn_global_load_lds(
      (const __attribute__((address_space(1))) unsigned int*)g,
      (__attribute__((address_space(3))) unsigned int*)l, 16, 0, 0);
}

__device__ __forceinline__ f32x4v mfma16(f16x8v a, f16x8v b, f32x4v c) {
  return __builtin_amdgcn_mfma_f32_16x16x32_f16(a, b, c, 0, 0, 0);
}
__device__ __forceinline__ f32x4v mfma16(bf16x8v a, bf16x8v b, f32x4v c) {
  return __builtin_amdgcn_mfma_f32_16x16x32_bf16(a, b, c, 0, 0, 0);
}

__device__ __forceinline__ unsigned short hbits(float f) {
  __half h = __float2half(f);
  unsigned short b; __builtin_memcpy(&b, &h, 2); return b;
}
__device__ __forceinline__ unsigned short bbits(float f) {
  __hip_bfloat16 h = __float2bfloat16(f);
  unsigned short b; __builtin_memcpy(&b, &h, 2); return b;
}

// ---------------------------------------------------------------------------
// 128x128-tile B^T GEMM, now BK-parametric. C[m,n] = sum_k A[m,k]*B[n,k].
// 256 thr = 4 waves, each a 64x64 quadrant. C/D: col=lane&15, row=quad*4+reg.
// BK=32 reduces byte-identically to the round-0 proven version (XOR mask 0).
// BK=64 (round 4): 128B-per-row-visit staging reads + half the barrier
// rounds + chunk-XOR LDS swizzle (BK=64 rows are 128B -> every row starts
// at bank 0 unswizzled; c^(r&7) spreads 16 frag rows to 2-way = free).
// Same mechanism that took mgemm_ag 74.6 -> ~45us in round 3.
// Epilogues are the round-0 PROVEN ones (round-1 lesson: stores must stay
// contiguous within 16 consecutive lanes; swapped layouts inflate WRITE 1.5x).
// MODE 0: DUAL theta+phi (blockIdx.z>>2 selects B/bias/out). fp16, +bias[n].
// MODE 1: bf16, +bias[m]                       (g proj -> gB [IC,H])
// MODE 2: bf16 exp(v); Z[b,n] += column sums   (scores -> E [q,k])
// MODE 3: fp32, +bias[m] + xres                (final + residual)
// ---------------------------------------------------------------------------
template <int MODE, int BK>
__launch_bounds__(256)
__global__ void mgemm128(const void* __restrict__ Aall, const void* __restrict__ Ball,
                         const void* __restrict__ Ball2,
                         void* __restrict__ outP, void* __restrict__ out2P,
                         const float* __restrict__ bias, const float* __restrict__ bias2,
                         const float* __restrict__ xres, float* __restrict__ Z,
                         int M, int N, int K,
                         size_t sAb, size_t sBb, size_t sOb) {
  using ET = typename std::conditional<MODE == 3, bf16x8v, f16x8v>::type;

  constexpr int CPR = BK / 8;              // 16B chunks per LDS row
  constexpr int XM = (BK >= 64) ? 7 : 0;   // chunk-XOR swizzle mask

  __shared__ __align__(16) unsigned short sA[128 * BK];
  __shared__ __align__(16) unsigned short sB[128 * BK];

  const int zz = blockIdx.z;
  int b, which;
  if constexpr (MODE == 0) { b = zz & (BB - 1); which = zz >> 2; }
  else { b = zz; which = 0; }

  const unsigned short* __restrict__ A = (const unsigned short*)Aall + (size_t)b * sAb;
  const unsigned short* __restrict__ Bm =
      (const unsigned short*)((MODE == 0 && which) ? Ball2 : Ball) + (size_t)b * sBb;
  const float* __restrict__ biasSel = (MODE == 0 && which) ? bias2 : bias;
  void* __restrict__ outSel = (MODE == 0 && which) ? out2P : outP;

  const int t = threadIdx.x;
  const int lane = t & 63;
  const int w = t >> 6;
  const int wm = (w >> 1) << 6;
  const int wn = (w & 1) << 6;
  const int mBase = blockIdx.y * 128;
  const int nBase = blockIdx.x * 128;

  const int fr = lane & 15;
  const int fo = (lane >> 4) << 3;   // 0,8,16,24 shorts within the 32-k slice
  const int fc = fo >> 3;            // 16B sub-chunk index 0..3

  f32x4v acc[4][4] = {};

  for (int k0 = 0; k0 < K; k0 += BK) {
    // stage: 128 rows x BK k per operand = 128*CPR chunks; CPR/2 per thread
#pragma unroll
    for (int p = 0; p < CPR / 2; ++p) {
      const int u = t + (p << 8);
      const int r = u / CPR;
      const int c = u & (CPR - 1);
      const int cs = (c ^ (r & XM)) << 3;
      gll16(A + (size_t)(mBase + r) * K + (k0 + cs), sA + u * 8);
      gll16(Bm + (size_t)(nBase + r) * K + (k0 + cs), sB + u * 8);
    }
    __syncthreads();
#pragma unroll
    for (int ks = 0; ks < BK / 32; ++ks) {
      ET af[4], bf[4];
#pragma unroll
      for (int i = 0; i < 4; ++i) {
        const int row = wm + (i << 4) + fr;
        const int phys = ((ks << 2) + fc) ^ (row & XM);
        af[i] = *(const ET*)(sA + row * BK + (phys << 3));
      }
#pragma unroll
      for (int j = 0; j < 4; ++j) {
        const int row = wn + (j << 4) + fr;
        const int phys = ((ks << 2) + fc) ^ (row & XM);
        bf[j] = *(const ET*)(sB + row * BK + (phys << 3));
      }
#pragma unroll
      for (int i = 0; i < 4; ++i)
#pragma unroll
        for (int j = 0; j < 4; ++j)
          acc[i][j] = mfma16(af[i], bf[j], acc[i][j]);
    }
    __syncthreads();
  }

  const int row0 = (lane >> 4) << 2;
  const int col = lane & 15;

  if constexpr (MODE == 2) {
    __hip_bfloat16* __restrict__ outB = (__hip_bfloat16*)outP;
    float csum[4] = {0.f, 0.f, 0.f, 0.f};
#pragma unroll
    for (int i = 0; i < 4; ++i) {
      const int m0 = mBase + wm + (i << 4) + row0;
#pragma unroll
      for (int j = 0; j < 4; ++j) {
        const int n = nBase + wn + (j << 4) + col;
        __hip_bfloat16* dst = outB + (size_t)b * sOb + (size_t)m0 * N + n;
#pragma unroll
        for (int rg = 0; rg < 4; ++rg) {
          const float e = __expf(acc[i][j][rg]);
          dst[(size_t)rg * N] = __float2bfloat16(e);
          csum[j] += e;
        }
      }
    }
#pragma unroll
    for (int j = 0; j < 4; ++j) {
      float s = csum[j];
      s += __shfl_xor(s, 16, 64);
      s += __shfl_xor(s, 32, 64);
      if (lane < 16) {
        const int n = nBase + wn + (j << 4) + col;
        atomicAdd(&Z[(size_t)b * N + n], s);
      }
    }
  } else {
#pragma unroll
    for (int i = 0; i < 4; ++i) {
      const int m0 = mBase + wm + (i << 4) + row0;
#pragma unroll
      for (int j = 0; j < 4; ++j) {
        const int n = nBase + wn + (j << 4) + col;
#pragma unroll
        for (int rg = 0; rg < 4; ++rg) {
          const int m = m0 + rg;
          const float v = acc[i][j][rg];
          if constexpr (MODE == 0) {
            ((__half*)outSel)[(size_t)b * sOb + (size_t)m * N + n] =
                __float2half(v + biasSel[n]);
          } else if constexpr (MODE == 1) {
            ((__hip_bfloat16*)outP)[(size_t)b * sOb + (size_t)m * N + n] =
                __float2bfloat16(v + bias[m]);
          } else {
            const size_t o = (size_t)b * sOb + (size_t)m * N + n;
            ((float*)outP)[o] = v + bias[m] + xres[o];
          }
        }
      }
    }
  }
}

// ---------------------------------------------------------------------------
// ag GEMM v3 (round-3 PROVEN: 74.6 -> ~45us). BK=128 (256B-contiguous E
// reads) + chunk-XOR swizzled LDS, split-K=2, single-buffered.
// Partial tiles -> fp16 packed ushort4 stores into P16[kc][b][q][ic].
// ---------------------------------------------------------------------------
__launch_bounds__(256)
__global__ void mgemm_ag(const __hip_bfloat16* __restrict__ Gall,
                         const __hip_bfloat16* __restrict__ Eall,
                         unsigned short* __restrict__ P16) {
  constexpr int KC = 2048;
  constexpr int BK = 128;
  __shared__ __align__(16) unsigned short sG[256 * BK];  // 64 KB
  __shared__ __align__(16) unsigned short sE[64 * BK];   // 16 KB

  const int b = blockIdx.z;
  const int kc = blockIdx.x;            // 0..1
  const int qBase = blockIdx.y * 64;
  const int k0base = kc * KC;

  const unsigned short* __restrict__ G =
      (const unsigned short*)Gall + (size_t)b * IC * HH;
  const unsigned short* __restrict__ E =
      (const unsigned short*)Eall + (size_t)b * HH * HH;

  const int t = threadIdx.x;
  const int lane = t & 63;
  const int w = t >> 6;
  const int fr = lane & 15;
  const int fo = (lane >> 4) << 3;      // 0,8,16,24 shorts
  const int fc = fo >> 3;               // chunk sub-index 0..3

  f32x4v acc[4][4] = {};

  for (int kk = 0; kk < KC; kk += BK) {
    const int k0 = k0base + kk;
    // stage E first (HBM, long latency): 64 rows x 128k = 1024 chunks
#pragma unroll
    for (int p = 0; p < 4; ++p) {
      const int u = t + (p << 8);
      const int row = u >> 4;
      const int csrc = (u & 15) ^ (row & 7);
      gll16(E + (size_t)(qBase + row) * HH + k0 + (csrc << 3), sE + u * 8);
    }
    // stage G (mostly L2): 256 rows x 128k = 4096 chunks
#pragma unroll
    for (int p = 0; p < 16; ++p) {
      const int u = t + (p << 8);
      const int row = u >> 4;
      const int csrc = (u & 15) ^ (row & 7);
      gll16(G + (size_t)row * HH + k0 + (csrc << 3), sG + u * 8);
    }
    __syncthreads();
#pragma unroll
    for (int ks = 0; ks < 4; ++ks) {
      bf16x8v af[4], bfv[4];
      const int c16 = (ks << 2) + fc;
#pragma unroll
      for (int i = 0; i < 4; ++i) {
        const int row = (w << 6) + (i << 4) + fr;
        af[i] = *(const bf16x8v*)(sG + row * BK + ((c16 ^ (row & 7)) << 3));
      }
#pragma unroll
      for (int j = 0; j < 4; ++j) {
        const int row = (j << 4) + fr;
        bfv[j] = *(const bf16x8v*)(sE + row * BK + ((c16 ^ (row & 7)) << 3));
      }
#pragma unroll
      for (int i = 0; i < 4; ++i)
#pragma unroll
        for (int j = 0; j < 4; ++j)
          acc[i][j] = mfma16(af[i], bfv[j], acc[i][j]);
    }
    __syncthreads();
  }

  // D layout: col(n=q)=lane&15, row(m=ic)=quad*4+reg -> packed 8B ushort4
  unsigned short* __restrict__ P =
      P16 + ((size_t)kc * BB + b) * HH * IC;
  const int quad = lane >> 4;
  const int col = lane & 15;
#pragma unroll
  for (int i = 0; i < 4; ++i) {
    const int ic0 = (w << 6) + (i << 4) + (quad << 2);
#pragma unroll
    for (int j = 0; j < 4; ++j) {
      const int q = qBase + (j << 4) + col;
      ushort4 s = {hbits(acc[i][j][0]), hbits(acc[i][j][1]),
                   hbits(acc[i][j][2]), hbits(acc[i][j][3])};
      *(ushort4*)(P + (size_t)q * IC + ic0) = s;
    }
  }
}

// agB[b,q,ic] = bf16( sum over 2 split-K chunks of fp16 P16 ), 8 elems/thread
__launch_bounds__(256)
__global__ void cvt_ag(const unsigned short* __restrict__ P16,
                       __hip_bfloat16* __restrict__ agB) {
  constexpr size_t CH = (size_t)BB * HH * IC;
  const size_t tIdx = (size_t)blockIdx.x * 256 + threadIdx.x;
  const f16x8v v0 = ((const f16x8v*)(P16))[tIdx];
  const f16x8v v1 = ((const f16x8v*)(P16 + CH))[tIdx];
  unsigned short o[8];
#pragma unroll
  for (int k = 0; k < 8; ++k) {
    const float s = (float)v0[k] + (float)v1[k];
    o[k] = bbits(s);
  }
  uint4 pack;
  __builtin_memcpy(&pack, o, 16);
  ((uint4*)agB)[tIdx] = pack;
}

// x [B,C,H] fp32 -> xT [B,H,C] fp16
__launch_bounds__(256)
__global__ void xpose(const float* __restrict__ x, __half* __restrict__ xT) {
  __shared__ float tile[64][65];
  const int b = blockIdx.z;
  const int h0 = blockIdx.x * 64;
  const int c0 = blockIdx.y * 64;
  const int lane = threadIdx.x & 63;
  const int r0 = threadIdx.x >> 6;
  const float* xb = x + (size_t)b * CC * HH;
#pragma unroll
  for (int rr = 0; rr < 16; ++rr) {
    const int c = r0 * 16 + rr;
    tile[c][lane] = xb[(size_t)(c0 + c) * HH + h0 + lane];
  }
  __syncthreads();
  __half* ob = xT + (size_t)b * HH * CC;
#pragma unroll
  for (int rr = 0; rr < 16; ++rr) {
    const int hl = r0 * 16 + rr;
    ob[(size_t)(h0 + hl) * CC + c0 + lane] = __float2half(tile[lane][hl]);
  }
}

__global__ void convw(const float* __restrict__ s0, const float* __restrict__ s1,
                      const float* __restrict__ s2, const float* __restrict__ s3,
                      __half* __restrict__ d0, __half* __restrict__ d1,
                      __half* __restrict__ d2, __hip_bfloat16* __restrict__ d3) {
  const int which = blockIdx.y;
  const int i = (blockIdx.x * 256 + threadIdx.x) * 4;
  if (which < 3) {
    const float* s = which == 0 ? s0 : (which == 1 ? s1 : s2);
    __half* d = which == 0 ? d0 : (which == 1 ? d1 : d2);
    const float4 v = *(const float4*)(s + i);
    d[i] = __float2half(v.x); d[i + 1] = __float2half(v.y);
    d[i + 2] = __float2half(v.z); d[i + 3] = __float2half(v.w);
  } else {
    const float4 v = *(const float4*)(s3 + i);
    d3[i] = __float2bfloat16(v.x); d3[i + 1] = __float2bfloat16(v.y);
    d3[i + 2] = __float2bfloat16(v.z); d3[i + 3] = __float2bfloat16(v.w);
  }
}

// gB [B,IC,H] bf16 /= Z[b,h]
__launch_bounds__(256)
__global__ void gscale(unsigned int* __restrict__ g, const float* __restrict__ Z) {
  const size_t tid = (size_t)blockIdx.x * 256 + threadIdx.x;
  const size_t e0 = tid * 8;
  const int b = (int)(e0 >> 20);
  const int h = (int)(e0 & (HH - 1));
  const float* Zp = Z + ((size_t)b << 12) + h;
  uint4 raw = ((const uint4*)g)[tid];
  unsigned short* u = (unsigned short*)&raw;
#pragma unroll
  for (int k = 0; k < 8; ++k) {
    const float f = __uint_as_float(((unsigned)u[k]) << 16) / Zp[k];
    u[k] = bbits(f);
  }
  ((uint4*)g)[tid] = raw;
}

// ---------------------------------------------------------------------------
extern "C" void kernel_launch(void* const* d_in, const int* in_sizes, int n_in,
                              void* d_out, int out_size, void* d_ws, size_t ws_size,
                              hipStream_t stream) {
  (void)in_sizes; (void)n_in; (void)out_size; (void)ws_size;

  const float* x       = (const float*)d_in[0];
  const float* w_phi   = (const float*)d_in[1];
  const float* b_phi   = (const float*)d_in[2];
  const float* w_theta = (const float*)d_in[3];
  const float* b_theta = (const float*)d_in[4];
  const float* w_g     = (const float*)d_in[5];
  const float* b_g     = (const float*)d_in[6];
  const float* w_mask  = (const float*)d_in[7];
  const float* b_mask  = (const float*)d_in[8];
  float* out = (float*)d_out;

  char* p = (char*)d_ws;
  __hip_bfloat16* E = (__hip_bfloat16*)p;           p += (size_t)BB * HH * HH * 2;   // [q][k]
  __half* xT       = (__half*)p;                    p += (size_t)BB * HH * CC * 2;   // 16.8 MB
  __half* thetaH   = (__half*)p;                    p += (size_t)BB * HH * IC * 2;   // [h][ic]
  __half* phiH     = (__half*)p;                    p += (size_t)BB * HH * IC * 2;   // [h][ic]
  __hip_bfloat16* gB  = (__hip_bfloat16*)p;         p += (size_t)BB * IC * HH * 2;   // [ic][h]
  __hip_bfloat16* agB = (__hip_bfloat16*)p;         p += (size_t)BB * HH * IC * 2;   // [h][ic]
  __half* wthH = (__half*)p;                        p += (size_t)IC * CC * 2;
  __half* wphH = (__half*)p;                        p += (size_t)IC * CC * 2;
  __half* wgH  = (__half*)p;                        p += (size_t)IC * CC * 2;
  __hip_bfloat16* wmB = (__hip_bfloat16*)p;         p += (size_t)CC * IC * 2;
  float* Z = (float*)p;                             p += (size_t)BB * HH * 4;
  // fp16 split-K=2 partials (2 x 8.4 MB = 16.8 MB) alias xT exactly; xT is
  // dead by the time mgemm_ag runs.
  unsigned short* P16 = (unsigned short*)xT;

  const dim3 blk(256);

  convw<<<dim3(128, 4), blk, 0, stream>>>(w_phi, w_theta, w_g, w_mask, wphH, wthH, wgH, wmB);
  xpose<<<dim3(HH / 64, CC / 64, BB), blk, 0, stream>>>(x, xT);

  // theta/phi dual: A=xT [H,C], B=w_theta/w_phi [IC,C]; out [h][ic] fp16, +bias[ic]
  mgemm128<0, 64><<<dim3(IC / 128, HH / 128, BB * 2), blk, 0, stream>>>(
      xT, wthH, wphH, thetaH, phiH, b_theta, b_phi, nullptr, nullptr,
      HH, IC, CC, (size_t)HH * CC, 0, (size_t)HH * IC);

  // g: A=wg [IC,C], B=xT [H,C]; out gB[ic][h] bf16, +bias[ic=m]
  mgemm128<1, 64><<<dim3(HH / 128, IC / 128, BB), blk, 0, stream>>>(
      wgH, xT, nullptr, gB, nullptr, b_g, nullptr, nullptr, nullptr,
      IC, HH, CC, 0, (size_t)HH * CC, (size_t)IC * HH);

  // scores: A=theta (m=q), B=phi (n=k); E[q][k] bf16 + Z[b,k]
  hipMemsetAsync(Z, 0, (size_t)BB * HH * sizeof(float), stream);
  mgemm128<2, 64><<<dim3(HH / 128, HH / 128, BB), blk, 0, stream>>>(
      thetaH, phiH, nullptr, E, nullptr, nullptr, nullptr, nullptr, Z,
      HH, HH, IC, (size_t)HH * IC, (size_t)HH * IC, (size_t)HH * HH);

  gscale<<<dim3((BB * IC * HH / 8) / 256), blk, 0, stream>>>((unsigned int*)gB, Z);

  // ag: BK=128 (256B-contiguous E reads), split-K=2, XOR-swizzled LDS
  mgemm_ag<<<dim3(2, HH / 64, BB), blk, 0, stream>>>(gB, E, P16);
  cvt_ag<<<dim3((BB * HH * IC / 8) / 256), blk, 0, stream>>>(P16, agB);

  // final: A=wm [C,IC], B=agB [H,IC]; out[c][h] fp32 + bias[c] + x
  mgemm128<3, 64><<<dim3(HH / 128, CC / 128, BB), blk, 0, stream>>>(
      wmB, agB, nullptr, out, nullptr, b_mask, nullptr, x, nullptr,
      CC, HH, IC, 0, (size_t)HH * IC, (size_t)CC * HH);
}